// Round 2
// baseline (2870.150 us; speedup 1.0000x reference)
//
#include <hip/hip_runtime.h>
#include <hip/hip_bf16.h>
#include <math.h>

#define N0 50000
#define E0 1600000
#define K1 40000
#define K2 32000
#define FEAT 128
#define HID 128
#define EMB 64
#define NCLS 10

static __device__ __forceinline__ unsigned f2key(float f) {
    unsigned u = __float_as_uint(f);
    return (u & 0x80000000u) ? ~u : (u | 0x80000000u);
}

// ---------- dtype detection: are float tensors f32 or bf16? ----------
// If data is f32, the low 16 bits of each word are mantissa bits -> as bf16 they
// show uniform-random exponents (often >=143, i.e. |v|>=2^16). Real bf16 data
// from this problem (~N(0,1) scaled) never exceeds 2^16.
__global__ void detect_dtype_kernel(const unsigned* __restrict__ w, int n, int* __restrict__ flag) {
    __shared__ int tot;
    if (threadIdx.x == 0) tot = 0;
    __syncthreads();
    int cnt = 0;
    for (int i = threadIdx.x; i < n; i += 256) {
        unsigned lo = w[i] & 0xFFFFu;
        unsigned e = (lo >> 7) & 0xFFu;
        cnt += (e >= 143);
    }
    atomicAdd(&tot, cnt);
    __syncthreads();
    if (threadIdx.x == 0) flag[0] = (tot > n / 8) ? 1 : 0;  // 1 = f32, 0 = bf16
}

// ---------- conversions (flag-dispatched) ----------
static __device__ __forceinline__ float load_as_f32(const void* in, long long i, int isF32) {
    if (isF32) return ((const float*)in)[i];
    unsigned short h = ((const unsigned short*)in)[i];
    return __uint_as_float(((unsigned)h) << 16);
}

__global__ void to_f32_kernel(const void* __restrict__ in, float* __restrict__ out, int n,
                              const int* __restrict__ flag) {
    int i = blockIdx.x * 256 + threadIdx.x;
    if (i < n) out[i] = load_as_f32(in, i, *flag);
}

// wT[c*O + o] = w[o*C + c]
__global__ void to_f32_t_kernel(const void* __restrict__ in, float* __restrict__ wT, int O, int C,
                                const int* __restrict__ flag) {
    int i = blockIdx.x * 256 + threadIdx.x;
    if (i >= O * C) return;
    int o = i / C, c = i % C;
    wT[c * O + o] = load_as_f32(in, i, *flag);
}

// ---------- CSR build ----------
__global__ void deg_count_kernel(const int* __restrict__ src, const int* __restrict__ dst, int E,
                                 const int* __restrict__ m1, const int* __restrict__ m2,
                                 int* __restrict__ deg) {
    int e = blockIdx.x * 256 + threadIdx.x;
    if (e >= E) return;
    int s = src[e], d = dst[e];
    if (m1) { s = m1[s]; d = m1[d]; if (s < 0 || d < 0) return; }
    if (m2) { s = m2[s]; d = m2[d]; if (s < 0 || d < 0) return; }
    atomicAdd(&deg[d], 1);
}

__global__ void csr_fill_kernel(const int* __restrict__ src, const int* __restrict__ dst, int E,
                                const int* __restrict__ m1, const int* __restrict__ m2,
                                int* __restrict__ cursor, int* __restrict__ cols) {
    int e = blockIdx.x * 256 + threadIdx.x;
    if (e >= E) return;
    int s = src[e], d = dst[e];
    if (m1) { s = m1[s]; d = m1[d]; if (s < 0 || d < 0) return; }
    if (m2) { s = m2[s]; d = m2[d]; if (s < 0 || d < 0) return; }
    int p = atomicAdd(&cursor[d], 1);
    cols[p] = s;
}

// single-block exclusive scan of deg[0..M) -> rowptr[0..M]
__global__ void exclusive_scan_kernel(const int* __restrict__ deg, int* __restrict__ rowptr, int M) {
    __shared__ int part[1024];
    int t = threadIdx.x;
    int per = (M + 1023) / 1024;
    int s = 0;
    for (int k = 0; k < per; ++k) { int idx = t * per + k; if (idx < M) s += deg[idx]; }
    part[t] = s;
    __syncthreads();
    for (int off = 1; off < 1024; off <<= 1) {
        int v = 0;
        if (t >= off) v = part[t - off];
        __syncthreads();
        if (t >= off) part[t] += v;
        __syncthreads();
    }
    int run = (t > 0) ? part[t - 1] : 0;
    for (int k = 0; k < per; ++k) {
        int idx = t * per + k;
        if (idx < M) { rowptr[idx] = run; run += deg[idx]; }
    }
    if (t == 1023) rowptr[M] = part[1023];
}

__global__ void copy_int_kernel(const int* __restrict__ in, int* __restrict__ out, int n) {
    int i = blockIdx.x * 256 + threadIdx.x;
    if (i < n) out[i] = in[i];
}

// ---------- gather aggregation: agg[n] = sum_{j in CSR row n} x[cols[j]] ----------
template<int C>
__global__ void aggregate_kernel(const int* __restrict__ rowptr, const int* __restrict__ cols,
                                 const float* __restrict__ x, float* __restrict__ agg, int M) {
    const int CH = C / 4;
    const int NPB = 256 / CH;
    int n = blockIdx.x * NPB + threadIdx.x / CH;
    int c4 = threadIdx.x % CH;
    if (n >= M) return;
    int b = rowptr[n], e = rowptr[n + 1];
    float4 s = {0.f, 0.f, 0.f, 0.f};
    for (int j = b; j < e; ++j) {
        int src = cols[j];
        float4 v = ((const float4*)(x + (size_t)src * C))[c4];
        s.x += v.x; s.y += v.y; s.z += v.z; s.w += v.w;
    }
    ((float4*)(agg + (size_t)n * C))[c4] = s;
}

// ---------- fused dual linear + bias + relu ----------
template<int Cin, int Cout>
__global__ void linear_relu_kernel(int M, const float* __restrict__ inA, const float* __restrict__ wAT,
                                   const float* __restrict__ inB, const float* __restrict__ wBT,
                                   const float* __restrict__ bias, float* __restrict__ out) {
    constexpr int RPT = 4;
    constexpr int CG  = 256 / Cout;
    constexpr int RPB = CG * RPT;
    int col = threadIdx.x % Cout;
    int rg  = threadIdx.x / Cout;
    int row0 = blockIdx.x * RPB + rg * RPT;
    float bf = bias[col];
    float acc[RPT];
#pragma unroll
    for (int t = 0; t < RPT; ++t) acc[t] = bf;
    const float* pa[RPT]; const float* pb[RPT];
#pragma unroll
    for (int t = 0; t < RPT; ++t) {
        int r = row0 + t; if (r > M - 1) r = M - 1;
        pa[t] = inA + (size_t)r * Cin;
        pb[t] = inB + (size_t)r * Cin;
    }
    for (int c4 = 0; c4 < Cin / 4; ++c4) {
        float wa[4], wb[4];
#pragma unroll
        for (int j = 0; j < 4; ++j) {
            wa[j] = wAT[(c4 * 4 + j) * Cout + col];
            wb[j] = wBT[(c4 * 4 + j) * Cout + col];
        }
#pragma unroll
        for (int t = 0; t < RPT; ++t) {
            float4 av = ((const float4*)pa[t])[c4];
            float4 bv = ((const float4*)pb[t])[c4];
            acc[t] = fmaf(wa[0], av.x, acc[t]); acc[t] = fmaf(wa[1], av.y, acc[t]);
            acc[t] = fmaf(wa[2], av.z, acc[t]); acc[t] = fmaf(wa[3], av.w, acc[t]);
            acc[t] = fmaf(wb[0], bv.x, acc[t]); acc[t] = fmaf(wb[1], bv.y, acc[t]);
            acc[t] = fmaf(wb[2], bv.z, acc[t]); acc[t] = fmaf(wb[3], bv.w, acc[t]);
        }
    }
#pragma unroll
    for (int t = 0; t < RPT; ++t) {
        int r = row0 + t;
        if (r < M) out[(size_t)r * Cout + col] = fmaxf(acc[t], 0.f);
    }
}

// ---------- pooling score: tanh((x . w)/||w||), one wave per row ----------
template<int C>
__global__ void score_kernel(const float* __restrict__ xin, const float* __restrict__ w,
                             int M, float* __restrict__ score) {
    int row = blockIdx.x * 4 + (threadIdx.x >> 6);
    int lane = threadIdx.x & 63;
    if (row >= M) return;
    float p = 0.f, q = 0.f;
#pragma unroll
    for (int c = lane; c < C; c += 64) {
        float wc = w[c];
        float xc = xin[(size_t)row * C + c];
        p += xc * wc; q += wc * wc;
    }
#pragma unroll
    for (int off = 32; off >= 1; off >>= 1) {
        p += __shfl_xor(p, off, 64);
        q += __shfl_xor(q, off, 64);
    }
    if (lane == 0) {
        float arg = p / sqrtf(q);
        score[row] = (float)tanh((double)arg);  // double for rounding robustness at saturation
    }
}

__global__ void build_keys_kernel(const float* __restrict__ score, unsigned* __restrict__ keys, int N) {
    int i = blockIdx.x * 256 + threadIdx.x;
    if (i < N) keys[i] = f2key(score[i]);
}

// rank(i) = #{j : key_j > key_i  or (key_j == key_i and j < i)}  -- exact argsort position
__global__ void rank_count_kernel(const unsigned* __restrict__ keys, int N, int* __restrict__ rank) {
    int i = blockIdx.x * 256 + threadIdx.x;
    int S = gridDim.y;
    int per = (N + S - 1) / S;
    int j0 = blockIdx.y * per;
    int j1 = j0 + per; if (j1 > N) j1 = N;
    unsigned ki = (i < N) ? keys[i] : 0u;
    int cnt = 0;
    for (int j = j0; j < j1; ++j) {
        unsigned kj = keys[j];  // same address across all lanes -> broadcast
        cnt += (kj > ki) ? 1 : ((kj == ki && j < i) ? 1 : 0);
    }
    if (i < N) atomicAdd(&rank[i], cnt);
}

__global__ void finalize_perm_kernel(const int* __restrict__ rank, int N, int K,
                                     int* __restrict__ perm, int* __restrict__ mapping) {
    int i = blockIdx.x * 256 + threadIdx.x;
    if (i >= N) return;
    int r = rank[i];
    if (r < K) { perm[r] = i; mapping[i] = r; }
    else mapping[i] = -1;
}

// xp[j] = x[perm[j]] * score[perm[j]]
template<int C>
__global__ void pool_apply_kernel(const float* __restrict__ xin, const float* __restrict__ score,
                                  const int* __restrict__ perm, float* __restrict__ xp, int K) {
    const int CH = C / 4;
    int tid = blockIdx.x * 256 + threadIdx.x;
    int j = tid / CH, c4 = tid % CH;
    if (j >= K) return;
    int src = perm[j];
    float s = score[src];
    float4 v = ((const float4*)(xin + (size_t)src * C))[c4];
    v.x *= s; v.y *= s; v.z *= s; v.w *= s;
    ((float4*)(xp + (size_t)j * C))[c4] = v;
}

// u[j] = base[j] + (mapping[j]>=0 ? deep[mapping[j]] : 0)   (u may alias base)
template<int C>
__global__ void unpool_add_kernel(const float* __restrict__ base, const float* __restrict__ deep,
                                  const int* __restrict__ mapping, float* __restrict__ u, int M) {
    const int CH = C / 4;
    int tid = blockIdx.x * 256 + threadIdx.x;
    int j = tid / CH, c4 = tid % CH;
    if (j >= M) return;
    float4 v = ((const float4*)(base + (size_t)j * C))[c4];
    int m = mapping[j];
    if (m >= 0) {
        float4 d = ((const float4*)(deep + (size_t)m * C))[c4];
        v.x += d.x; v.y += d.y; v.z += d.z; v.w += d.w;
    }
    ((float4*)(u + (size_t)j * C))[c4] = v;
}

// log_softmax(x5 @ lin_w.T + lin_b); one wave per row; output dtype per flag
__global__ void head_kernel(const float* __restrict__ x5, const float* __restrict__ lw,
                            const float* __restrict__ lb, void* __restrict__ out, int M,
                            const int* __restrict__ flag) {
    int row = blockIdx.x * 4 + (threadIdx.x >> 6);
    int lane = threadIdx.x & 63;
    if (row >= M) return;
    float a0 = x5[(size_t)row * 128 + lane];
    float a1 = x5[(size_t)row * 128 + 64 + lane];
    float d[NCLS];
#pragma unroll
    for (int o = 0; o < NCLS; ++o) {
        float p = a0 * lw[o * 128 + lane] + a1 * lw[o * 128 + 64 + lane];
#pragma unroll
        for (int off = 32; off >= 1; off >>= 1) p += __shfl_xor(p, off, 64);
        d[o] = p + lb[o];
    }
    float mx = d[0];
#pragma unroll
    for (int o = 1; o < NCLS; ++o) mx = fmaxf(mx, d[o]);
    float s = 0.f;
#pragma unroll
    for (int o = 0; o < NCLS; ++o) s += expf(d[o] - mx);
    float lse = mx + logf(s);
    if (lane < NCLS) {
        float v = d[0];
#pragma unroll
        for (int o = 1; o < NCLS; ++o) if (lane == o) v = d[o];
        float r = v - lse;
        if (*flag) ((float*)out)[(size_t)row * NCLS + lane] = r;
        else ((__hip_bfloat16*)out)[(size_t)row * NCLS + lane] = __float2bfloat16(r);
    }
}

extern "C" void kernel_launch(void* const* d_in, const int* in_sizes, int n_in,
                              void* d_out, int out_size, void* d_ws, size_t ws_size,
                              hipStream_t stream) {
    const void* x_raw   = d_in[0];
    const int*  ei      = (const int*)d_in[1];
    const void* w1_rel  = d_in[2];
    const void* w1_root = d_in[3];
    const void* b1      = d_in[4];
    const void* p1w     = d_in[5];
    const void* w2_rel  = d_in[6];
    const void* w2_root = d_in[7];
    const void* b2      = d_in[8];
    const void* p2w     = d_in[9];
    const void* w3_rel  = d_in[10];
    const void* w3_root = d_in[11];
    const void* b3      = d_in[12];
    const void* w4_rel  = d_in[13];
    const void* w4_root = d_in[14];
    const void* b4      = d_in[15];
    const void* w5_rel  = d_in[16];
    const void* w5_root = d_in[17];
    const void* b5      = d_in[18];
    const void* lw      = d_in[19];
    const void* lb      = d_in[20];

    char* base = (char*)d_ws;
    size_t off = 0;
    auto alloc = [&](size_t bytes) -> void* {
        void* p = base + off;
        off = (off + bytes + 255) & ~(size_t)255;
        return p;
    };
    int*   flag  = (int*)alloc(256);
    float* w1rT  = (float*)alloc(HID * FEAT * 4);
    float* w1tT  = (float*)alloc(HID * FEAT * 4);
    float* w2rT  = (float*)alloc(EMB * HID * 4);
    float* w2tT  = (float*)alloc(EMB * HID * 4);
    float* w3rT  = (float*)alloc(EMB * EMB * 4);
    float* w3tT  = (float*)alloc(EMB * EMB * 4);
    float* w4rT  = (float*)alloc(HID * EMB * 4);
    float* w4tT  = (float*)alloc(HID * EMB * 4);
    float* w5rT  = (float*)alloc(FEAT * HID * 4);
    float* w5tT  = (float*)alloc(FEAT * HID * 4);
    float* b1f   = (float*)alloc(HID * 4);
    float* b2f   = (float*)alloc(EMB * 4);
    float* b3f   = (float*)alloc(EMB * 4);
    float* b4f   = (float*)alloc(HID * 4);
    float* b5f   = (float*)alloc(FEAT * 4);
    float* p1f   = (float*)alloc(HID * 4);
    float* p2f   = (float*)alloc(EMB * 4);
    float* lwf   = (float*)alloc(NCLS * FEAT * 4);
    float* lbf   = (float*)alloc(NCLS * 4);
    float* score = (float*)alloc((size_t)N0 * 4);
    unsigned* keys = (unsigned*)alloc((size_t)N0 * 4);
    int*   rank  = (int*)alloc((size_t)N0 * 4);
    int*   perm1 = (int*)alloc((size_t)K1 * 4);
    int*   map1  = (int*)alloc((size_t)N0 * 4);
    int*   perm2 = (int*)alloc((size_t)K2 * 4);
    int*   map2  = (int*)alloc((size_t)K1 * 4);
    int*   deg   = (int*)alloc((size_t)(N0 + 1) * 4);
    int*   cursor= (int*)alloc((size_t)(N0 + 1) * 4);
    int*   rp0   = (int*)alloc((size_t)(N0 + 1) * 4);
    int*   rp1   = (int*)alloc((size_t)(K1 + 1) * 4);
    int*   rp2   = (int*)alloc((size_t)(K2 + 1) * 4);
    int*   cols0 = (int*)alloc((size_t)E0 * 4);
    int*   cols1 = (int*)alloc((size_t)E0 * 4);
    int*   cols2 = (int*)alloc((size_t)E0 * 4);
    float* arenaA= (float*)alloc((size_t)N0 * 128 * 4);  // xf -> xp1 -> {xp2,x3} -> x4 -> x5
    float* agg   = (float*)alloc((size_t)N0 * 128 * 4);
    float* x1    = (float*)alloc((size_t)N0 * 128 * 4);  // becomes u2 in-place
    float* x2    = (float*)alloc((size_t)K1 * 64 * 4);
    float* u1    = (float*)alloc((size_t)K1 * 64 * 4);

    float* xf  = arenaA;
    float* xp1 = arenaA;
    float* xp2 = arenaA;
    float* x3  = arenaA + (size_t)10485760 / 4;  // +10MB, past xp2 (8.192MB)
    float* x4  = arenaA;
    float* x5  = arenaA;

    const int* src0 = ei;
    const int* dst0 = ei + E0;

    auto g = [](long long n, int b) -> unsigned { return (unsigned)((n + b - 1) / b); };

    // ---- dtype detect + conversions ----
    detect_dtype_kernel<<<1, 256, 0, stream>>>((const unsigned*)x_raw, 4096, flag);
    to_f32_kernel<<<g((long long)N0 * FEAT, 256), 256, 0, stream>>>(x_raw, xf, N0 * FEAT, flag);
    to_f32_t_kernel<<<g(HID * FEAT, 256), 256, 0, stream>>>(w1_rel,  w1rT, HID, FEAT, flag);
    to_f32_t_kernel<<<g(HID * FEAT, 256), 256, 0, stream>>>(w1_root, w1tT, HID, FEAT, flag);
    to_f32_t_kernel<<<g(EMB * HID, 256), 256, 0, stream>>>(w2_rel,  w2rT, EMB, HID, flag);
    to_f32_t_kernel<<<g(EMB * HID, 256), 256, 0, stream>>>(w2_root, w2tT, EMB, HID, flag);
    to_f32_t_kernel<<<g(EMB * EMB, 256), 256, 0, stream>>>(w3_rel,  w3rT, EMB, EMB, flag);
    to_f32_t_kernel<<<g(EMB * EMB, 256), 256, 0, stream>>>(w3_root, w3tT, EMB, EMB, flag);
    to_f32_t_kernel<<<g(HID * EMB, 256), 256, 0, stream>>>(w4_rel,  w4rT, HID, EMB, flag);
    to_f32_t_kernel<<<g(HID * EMB, 256), 256, 0, stream>>>(w4_root, w4tT, HID, EMB, flag);
    to_f32_t_kernel<<<g(FEAT * HID, 256), 256, 0, stream>>>(w5_rel,  w5rT, FEAT, HID, flag);
    to_f32_t_kernel<<<g(FEAT * HID, 256), 256, 0, stream>>>(w5_root, w5tT, FEAT, HID, flag);
    to_f32_kernel<<<1, 256, 0, stream>>>(b1, b1f, HID, flag);
    to_f32_kernel<<<1, 256, 0, stream>>>(b2, b2f, EMB, flag);
    to_f32_kernel<<<1, 256, 0, stream>>>(b3, b3f, EMB, flag);
    to_f32_kernel<<<1, 256, 0, stream>>>(b4, b4f, HID, flag);
    to_f32_kernel<<<1, 256, 0, stream>>>(b5, b5f, FEAT, flag);
    to_f32_kernel<<<1, 256, 0, stream>>>(p1w, p1f, HID, flag);
    to_f32_kernel<<<1, 256, 0, stream>>>(p2w, p2f, EMB, flag);
    to_f32_kernel<<<g(NCLS * FEAT, 256), 256, 0, stream>>>(lw, lwf, NCLS * FEAT, flag);
    to_f32_kernel<<<1, 256, 0, stream>>>(lb, lbf, NCLS, flag);

    // ---- CSR for graph0 ----
    hipMemsetAsync(deg, 0, (size_t)N0 * 4, stream);
    deg_count_kernel<<<g(E0, 256), 256, 0, stream>>>(src0, dst0, E0, nullptr, nullptr, deg);
    exclusive_scan_kernel<<<1, 1024, 0, stream>>>(deg, rp0, N0);
    copy_int_kernel<<<g(N0, 256), 256, 0, stream>>>(rp0, cursor, N0);
    csr_fill_kernel<<<g(E0, 256), 256, 0, stream>>>(src0, dst0, E0, nullptr, nullptr, cursor, cols0);

    // ---- Layer 1 ----
    aggregate_kernel<128><<<g(N0, 8), 256, 0, stream>>>(rp0, cols0, xf, agg, N0);
    linear_relu_kernel<128, 128><<<g(N0, 8), 256, 0, stream>>>(N0, agg, w1rT, xf, w1tT, b1f, x1);

    // ---- Pool 1 ----
    score_kernel<128><<<g(N0, 4), 256, 0, stream>>>(x1, p1f, N0, score);
    build_keys_kernel<<<g(N0, 256), 256, 0, stream>>>(score, keys, N0);
    hipMemsetAsync(rank, 0, (size_t)N0 * 4, stream);
    {
        dim3 grid(g(N0, 256), 16);
        rank_count_kernel<<<grid, 256, 0, stream>>>(keys, N0, rank);
    }
    finalize_perm_kernel<<<g(N0, 256), 256, 0, stream>>>(rank, N0, K1, perm1, map1);
    pool_apply_kernel<128><<<g((long long)K1 * 32, 256), 256, 0, stream>>>(x1, score, perm1, xp1, K1);

    // ---- CSR for graph1 ----
    hipMemsetAsync(deg, 0, (size_t)K1 * 4, stream);
    deg_count_kernel<<<g(E0, 256), 256, 0, stream>>>(src0, dst0, E0, map1, nullptr, deg);
    exclusive_scan_kernel<<<1, 1024, 0, stream>>>(deg, rp1, K1);
    copy_int_kernel<<<g(K1, 256), 256, 0, stream>>>(rp1, cursor, K1);
    csr_fill_kernel<<<g(E0, 256), 256, 0, stream>>>(src0, dst0, E0, map1, nullptr, cursor, cols1);

    // ---- Layer 2 ----
    aggregate_kernel<128><<<g(K1, 8), 256, 0, stream>>>(rp1, cols1, xp1, agg, K1);
    linear_relu_kernel<128, 64><<<g(K1, 16), 256, 0, stream>>>(K1, agg, w2rT, xp1, w2tT, b2f, x2);

    // ---- Pool 2 ----
    score_kernel<64><<<g(K1, 4), 256, 0, stream>>>(x2, p2f, K1, score);
    build_keys_kernel<<<g(K1, 256), 256, 0, stream>>>(score, keys, K1);
    hipMemsetAsync(rank, 0, (size_t)K1 * 4, stream);
    {
        dim3 grid(g(K1, 256), 16);
        rank_count_kernel<<<grid, 256, 0, stream>>>(keys, K1, rank);
    }
    finalize_perm_kernel<<<g(K1, 256), 256, 0, stream>>>(rank, K1, K2, perm2, map2);
    pool_apply_kernel<64><<<g((long long)K2 * 16, 256), 256, 0, stream>>>(x2, score, perm2, xp2, K2);

    // ---- CSR for graph2 ----
    hipMemsetAsync(deg, 0, (size_t)K2 * 4, stream);
    deg_count_kernel<<<g(E0, 256), 256, 0, stream>>>(src0, dst0, E0, map1, map2, deg);
    exclusive_scan_kernel<<<1, 1024, 0, stream>>>(deg, rp2, K2);
    copy_int_kernel<<<g(K2, 256), 256, 0, stream>>>(rp2, cursor, K2);
    csr_fill_kernel<<<g(E0, 256), 256, 0, stream>>>(src0, dst0, E0, map1, map2, cursor, cols2);

    // ---- Layer 3 ----
    aggregate_kernel<64><<<g(K2, 16), 256, 0, stream>>>(rp2, cols2, xp2, agg, K2);
    linear_relu_kernel<64, 64><<<g(K2, 16), 256, 0, stream>>>(K2, agg, w3rT, xp2, w3tT, b3f, x3);

    // ---- Unpool 1 ----
    unpool_add_kernel<64><<<g((long long)K1 * 16, 256), 256, 0, stream>>>(x2, x3, map2, u1, K1);

    // ---- Layer 4 ----
    aggregate_kernel<64><<<g(K1, 16), 256, 0, stream>>>(rp1, cols1, u1, agg, K1);
    linear_relu_kernel<64, 128><<<g(K1, 8), 256, 0, stream>>>(K1, agg, w4rT, u1, w4tT, b4f, x4);

    // ---- Unpool 2 (in-place on x1) ----
    unpool_add_kernel<128><<<g((long long)N0 * 32, 256), 256, 0, stream>>>(x1, x4, map1, x1, N0);

    // ---- Layer 5 ----
    aggregate_kernel<128><<<g(N0, 8), 256, 0, stream>>>(rp0, cols0, x1, agg, N0);
    linear_relu_kernel<128, 128><<<g(N0, 8), 256, 0, stream>>>(N0, agg, w5rT, x1, w5tT, b5f, x5);

    // ---- Head ----
    head_kernel<<<g(N0, 4), 256, 0, stream>>>(x5, lwf, lbf, d_out, N0, flag);
}

// Round 3
// 2312.475 us; speedup vs baseline: 1.2412x; 1.2412x over previous
//
#include <hip/hip_runtime.h>
#include <hip/hip_bf16.h>
#include <math.h>

#define N0 50000
#define E0 1600000
#define K1 40000
#define K2 32000
#define FEAT 128
#define HID 128
#define EMB 64
#define NCLS 10

static __device__ __forceinline__ unsigned f2key(float f) {
    unsigned u = __float_as_uint(f);
    return (u & 0x80000000u) ? ~u : (u | 0x80000000u);
}

// ---------- dtype detection: are float tensors f32 or bf16? ----------
__global__ void detect_dtype_kernel(const unsigned* __restrict__ w, int n, int* __restrict__ flag) {
    __shared__ int tot;
    if (threadIdx.x == 0) tot = 0;
    __syncthreads();
    int cnt = 0;
    for (int i = threadIdx.x; i < n; i += 256) {
        unsigned lo = w[i] & 0xFFFFu;
        unsigned e = (lo >> 7) & 0xFFu;
        cnt += (e >= 143);
    }
    atomicAdd(&tot, cnt);
    __syncthreads();
    if (threadIdx.x == 0) flag[0] = (tot > n / 8) ? 1 : 0;  // 1 = f32, 0 = bf16
}

static __device__ __forceinline__ float load_as_f32(const void* in, long long i, int isF32) {
    if (isF32) return ((const float*)in)[i];
    unsigned short h = ((const unsigned short*)in)[i];
    return __uint_as_float(((unsigned)h) << 16);
}

__global__ void to_f32_kernel(const void* __restrict__ in, float* __restrict__ out, int n,
                              const int* __restrict__ flag) {
    int i = blockIdx.x * 256 + threadIdx.x;
    if (i < n) out[i] = load_as_f32(in, i, *flag);
}

// wT[c*O + o] = w[o*C + c]
__global__ void to_f32_t_kernel(const void* __restrict__ in, float* __restrict__ wT, int O, int C,
                                const int* __restrict__ flag) {
    int i = blockIdx.x * 256 + threadIdx.x;
    if (i >= O * C) return;
    int o = i / C, c = i % C;
    wT[c * O + o] = load_as_f32(in, i, *flag);
}

// ---------- CSR build ----------
__global__ void deg_count_kernel(const int* __restrict__ src, const int* __restrict__ dst, int E,
                                 const int* __restrict__ m1, const int* __restrict__ m2,
                                 int* __restrict__ deg) {
    int e = blockIdx.x * 256 + threadIdx.x;
    if (e >= E) return;
    int s = src[e], d = dst[e];
    if (m1) { s = m1[s]; d = m1[d]; if (s < 0 || d < 0) return; }
    if (m2) { s = m2[s]; d = m2[d]; if (s < 0 || d < 0) return; }
    atomicAdd(&deg[d], 1);
}

__global__ void csr_fill_kernel(const int* __restrict__ src, const int* __restrict__ dst, int E,
                                const int* __restrict__ m1, const int* __restrict__ m2,
                                int* __restrict__ cursor, int* __restrict__ cols) {
    int e = blockIdx.x * 256 + threadIdx.x;
    if (e >= E) return;
    int s = src[e], d = dst[e];
    if (m1) { s = m1[s]; d = m1[d]; if (s < 0 || d < 0) return; }
    if (m2) { s = m2[s]; d = m2[d]; if (s < 0 || d < 0) return; }
    int p = atomicAdd(&cursor[d], 1);
    cols[p] = s;
}

__global__ void exclusive_scan_kernel(const int* __restrict__ deg, int* __restrict__ rowptr, int M) {
    __shared__ int part[1024];
    int t = threadIdx.x;
    int per = (M + 1023) / 1024;
    int s = 0;
    for (int k = 0; k < per; ++k) { int idx = t * per + k; if (idx < M) s += deg[idx]; }
    part[t] = s;
    __syncthreads();
    for (int off = 1; off < 1024; off <<= 1) {
        int v = 0;
        if (t >= off) v = part[t - off];
        __syncthreads();
        if (t >= off) part[t] += v;
        __syncthreads();
    }
    int run = (t > 0) ? part[t - 1] : 0;
    for (int k = 0; k < per; ++k) {
        int idx = t * per + k;
        if (idx < M) { rowptr[idx] = run; run += deg[idx]; }
    }
    if (t == 1023) rowptr[M] = part[1023];
}

__global__ void copy_int_kernel(const int* __restrict__ in, int* __restrict__ out, int n) {
    int i = blockIdx.x * 256 + threadIdx.x;
    if (i < n) out[i] = in[i];
}

// ---------- gather aggregation ----------
template<int C>
__global__ void aggregate_kernel(const int* __restrict__ rowptr, const int* __restrict__ cols,
                                 const float* __restrict__ x, float* __restrict__ agg, int M) {
    const int CH = C / 4;
    const int NPB = 256 / CH;
    int n = blockIdx.x * NPB + threadIdx.x / CH;
    int c4 = threadIdx.x % CH;
    if (n >= M) return;
    int b = rowptr[n], e = rowptr[n + 1];
    float4 s = {0.f, 0.f, 0.f, 0.f};
    for (int j = b; j < e; ++j) {
        int src = cols[j];
        float4 v = ((const float4*)(x + (size_t)src * C))[c4];
        s.x += v.x; s.y += v.y; s.z += v.z; s.w += v.w;
    }
    ((float4*)(agg + (size_t)n * C))[c4] = s;
}

// ---------- fused dual linear + bias + relu ----------
template<int Cin, int Cout>
__global__ void linear_relu_kernel(int M, const float* __restrict__ inA, const float* __restrict__ wAT,
                                   const float* __restrict__ inB, const float* __restrict__ wBT,
                                   const float* __restrict__ bias, float* __restrict__ out) {
    constexpr int RPT = 4;
    constexpr int CG  = 256 / Cout;
    constexpr int RPB = CG * RPT;
    int col = threadIdx.x % Cout;
    int rg  = threadIdx.x / Cout;
    int row0 = blockIdx.x * RPB + rg * RPT;
    float bf = bias[col];
    float acc[RPT];
#pragma unroll
    for (int t = 0; t < RPT; ++t) acc[t] = bf;
    const float* pa[RPT]; const float* pb[RPT];
#pragma unroll
    for (int t = 0; t < RPT; ++t) {
        int r = row0 + t; if (r > M - 1) r = M - 1;
        pa[t] = inA + (size_t)r * Cin;
        pb[t] = inB + (size_t)r * Cin;
    }
    for (int c4 = 0; c4 < Cin / 4; ++c4) {
        float wa[4], wb[4];
#pragma unroll
        for (int j = 0; j < 4; ++j) {
            wa[j] = wAT[(c4 * 4 + j) * Cout + col];
            wb[j] = wBT[(c4 * 4 + j) * Cout + col];
        }
#pragma unroll
        for (int t = 0; t < RPT; ++t) {
            float4 av = ((const float4*)pa[t])[c4];
            float4 bv = ((const float4*)pb[t])[c4];
            acc[t] = fmaf(wa[0], av.x, acc[t]); acc[t] = fmaf(wa[1], av.y, acc[t]);
            acc[t] = fmaf(wa[2], av.z, acc[t]); acc[t] = fmaf(wa[3], av.w, acc[t]);
            acc[t] = fmaf(wb[0], bv.x, acc[t]); acc[t] = fmaf(wb[1], bv.y, acc[t]);
            acc[t] = fmaf(wb[2], bv.z, acc[t]); acc[t] = fmaf(wb[3], bv.w, acc[t]);
        }
    }
#pragma unroll
    for (int t = 0; t < RPT; ++t) {
        int r = row0 + t;
        if (r < M) out[(size_t)r * Cout + col] = fmaxf(acc[t], 0.f);
    }
}

// ---------- pooling score ----------
template<int C>
__global__ void score_kernel(const float* __restrict__ xin, const float* __restrict__ w,
                             int M, float* __restrict__ score) {
    int row = blockIdx.x * 4 + (threadIdx.x >> 6);
    int lane = threadIdx.x & 63;
    if (row >= M) return;
    float p = 0.f, q = 0.f;
#pragma unroll
    for (int c = lane; c < C; c += 64) {
        float wc = w[c];
        float xc = xin[(size_t)row * C + c];
        p += xc * wc; q += wc * wc;
    }
#pragma unroll
    for (int off = 32; off >= 1; off >>= 1) {
        p += __shfl_xor(p, off, 64);
        q += __shfl_xor(q, off, 64);
    }
    if (lane == 0) {
        float arg = p / sqrtf(q);
        score[row] = (float)tanh((double)arg);
    }
}

// composite key: (f2key(score) << 32) | ~index  -- all distinct; order = (score desc, idx asc) descending
__global__ void build_keys_kernel(const float* __restrict__ score, unsigned long long* __restrict__ keys, int N) {
    int i = blockIdx.x * 256 + threadIdx.x;
    if (i < N) keys[i] = ((unsigned long long)f2key(score[i]) << 32) | (unsigned)(~i);
}

// rank(i) = #{j : ckey_j > ckey_i}  -- exact argsort position; j-tiles staged in LDS
#define RT 4096
__global__ void rank_count_kernel(const unsigned long long* __restrict__ keys, int N, int* __restrict__ rank) {
    __shared__ unsigned long long sk[RT];
    int i = blockIdx.x * 256 + threadIdx.x;
    int j0 = blockIdx.y * RT;
    int tile = N - j0; if (tile > RT) tile = RT;
    for (int t = threadIdx.x; t < tile; t += 256) sk[t] = keys[j0 + t];
    __syncthreads();
    unsigned long long ci = (i < N) ? keys[i] : ~0ull;
    int cnt = 0;
    int t = 0;
    for (; t + 8 <= tile; t += 8) {
        cnt += (sk[t+0] > ci); cnt += (sk[t+1] > ci);
        cnt += (sk[t+2] > ci); cnt += (sk[t+3] > ci);
        cnt += (sk[t+4] > ci); cnt += (sk[t+5] > ci);
        cnt += (sk[t+6] > ci); cnt += (sk[t+7] > ci);
    }
    for (; t < tile; ++t) cnt += (sk[t] > ci);
    if (i < N && cnt) atomicAdd(&rank[i], cnt);
}

__global__ void finalize_perm_kernel(const int* __restrict__ rank, int N, int K,
                                     int* __restrict__ perm, int* __restrict__ mapping) {
    int i = blockIdx.x * 256 + threadIdx.x;
    if (i >= N) return;
    int r = rank[i];
    if (r < K) { perm[r] = i; mapping[i] = r; }
    else mapping[i] = -1;
}

template<int C>
__global__ void pool_apply_kernel(const float* __restrict__ xin, const float* __restrict__ score,
                                  const int* __restrict__ perm, float* __restrict__ xp, int K) {
    const int CH = C / 4;
    int tid = blockIdx.x * 256 + threadIdx.x;
    int j = tid / CH, c4 = tid % CH;
    if (j >= K) return;
    int src = perm[j];
    float s = score[src];
    float4 v = ((const float4*)(xin + (size_t)src * C))[c4];
    v.x *= s; v.y *= s; v.z *= s; v.w *= s;
    ((float4*)(xp + (size_t)j * C))[c4] = v;
}

template<int C>
__global__ void unpool_add_kernel(const float* __restrict__ base, const float* __restrict__ deep,
                                  const int* __restrict__ mapping, float* __restrict__ u, int M) {
    const int CH = C / 4;
    int tid = blockIdx.x * 256 + threadIdx.x;
    int j = tid / CH, c4 = tid % CH;
    if (j >= M) return;
    float4 v = ((const float4*)(base + (size_t)j * C))[c4];
    int m = mapping[j];
    if (m >= 0) {
        float4 d = ((const float4*)(deep + (size_t)m * C))[c4];
        v.x += d.x; v.y += d.y; v.z += d.z; v.w += d.w;
    }
    ((float4*)(u + (size_t)j * C))[c4] = v;
}

__global__ void head_kernel(const float* __restrict__ x5, const float* __restrict__ lw,
                            const float* __restrict__ lb, void* __restrict__ out, int M,
                            const int* __restrict__ flag) {
    int row = blockIdx.x * 4 + (threadIdx.x >> 6);
    int lane = threadIdx.x & 63;
    if (row >= M) return;
    float a0 = x5[(size_t)row * 128 + lane];
    float a1 = x5[(size_t)row * 128 + 64 + lane];
    float d[NCLS];
#pragma unroll
    for (int o = 0; o < NCLS; ++o) {
        float p = a0 * lw[o * 128 + lane] + a1 * lw[o * 128 + 64 + lane];
#pragma unroll
        for (int off = 32; off >= 1; off >>= 1) p += __shfl_xor(p, off, 64);
        d[o] = p + lb[o];
    }
    float mx = d[0];
#pragma unroll
    for (int o = 1; o < NCLS; ++o) mx = fmaxf(mx, d[o]);
    float s = 0.f;
#pragma unroll
    for (int o = 0; o < NCLS; ++o) s += expf(d[o] - mx);
    float lse = mx + logf(s);
    if (lane < NCLS) {
        float v = d[0];
#pragma unroll
        for (int o = 1; o < NCLS; ++o) if (lane == o) v = d[o];
        float r = v - lse;
        if (*flag) ((float*)out)[(size_t)row * NCLS + lane] = r;
        else ((__hip_bfloat16*)out)[(size_t)row * NCLS + lane] = __float2bfloat16(r);
    }
}

extern "C" void kernel_launch(void* const* d_in, const int* in_sizes, int n_in,
                              void* d_out, int out_size, void* d_ws, size_t ws_size,
                              hipStream_t stream) {
    const void* x_raw   = d_in[0];
    const int*  ei      = (const int*)d_in[1];
    const void* w1_rel  = d_in[2];
    const void* w1_root = d_in[3];
    const void* b1      = d_in[4];
    const void* p1w     = d_in[5];
    const void* w2_rel  = d_in[6];
    const void* w2_root = d_in[7];
    const void* b2      = d_in[8];
    const void* p2w     = d_in[9];
    const void* w3_rel  = d_in[10];
    const void* w3_root = d_in[11];
    const void* b3      = d_in[12];
    const void* w4_rel  = d_in[13];
    const void* w4_root = d_in[14];
    const void* b4      = d_in[15];
    const void* w5_rel  = d_in[16];
    const void* w5_root = d_in[17];
    const void* b5      = d_in[18];
    const void* lw      = d_in[19];
    const void* lb      = d_in[20];

    char* base = (char*)d_ws;
    size_t off = 0;
    auto alloc = [&](size_t bytes) -> void* {
        void* p = base + off;
        off = (off + bytes + 255) & ~(size_t)255;
        return p;
    };
    int*   flag  = (int*)alloc(256);
    float* w1rT  = (float*)alloc(HID * FEAT * 4);
    float* w1tT  = (float*)alloc(HID * FEAT * 4);
    float* w2rT  = (float*)alloc(EMB * HID * 4);
    float* w2tT  = (float*)alloc(EMB * HID * 4);
    float* w3rT  = (float*)alloc(EMB * EMB * 4);
    float* w3tT  = (float*)alloc(EMB * EMB * 4);
    float* w4rT  = (float*)alloc(HID * EMB * 4);
    float* w4tT  = (float*)alloc(HID * EMB * 4);
    float* w5rT  = (float*)alloc(FEAT * HID * 4);
    float* w5tT  = (float*)alloc(FEAT * HID * 4);
    float* b1f   = (float*)alloc(HID * 4);
    float* b2f   = (float*)alloc(EMB * 4);
    float* b3f   = (float*)alloc(EMB * 4);
    float* b4f   = (float*)alloc(HID * 4);
    float* b5f   = (float*)alloc(FEAT * 4);
    float* p1f   = (float*)alloc(HID * 4);
    float* p2f   = (float*)alloc(EMB * 4);
    float* lwf   = (float*)alloc(NCLS * FEAT * 4);
    float* lbf   = (float*)alloc(NCLS * 4);
    float* score = (float*)alloc((size_t)N0 * 4);
    unsigned long long* keys = (unsigned long long*)alloc((size_t)N0 * 8);
    int*   rank  = (int*)alloc((size_t)N0 * 4);
    int*   perm1 = (int*)alloc((size_t)K1 * 4);
    int*   map1  = (int*)alloc((size_t)N0 * 4);
    int*   perm2 = (int*)alloc((size_t)K2 * 4);
    int*   map2  = (int*)alloc((size_t)K1 * 4);
    int*   deg   = (int*)alloc((size_t)(N0 + 1) * 4);
    int*   cursor= (int*)alloc((size_t)(N0 + 1) * 4);
    int*   rp0   = (int*)alloc((size_t)(N0 + 1) * 4);
    int*   rp1   = (int*)alloc((size_t)(K1 + 1) * 4);
    int*   rp2   = (int*)alloc((size_t)(K2 + 1) * 4);
    int*   cols0 = (int*)alloc((size_t)E0 * 4);
    int*   cols1 = (int*)alloc((size_t)E0 * 4);
    int*   cols2 = (int*)alloc((size_t)E0 * 4);
    float* arenaA= (float*)alloc((size_t)N0 * 128 * 4);
    float* agg   = (float*)alloc((size_t)N0 * 128 * 4);
    float* x1    = (float*)alloc((size_t)N0 * 128 * 4);
    float* x2    = (float*)alloc((size_t)K1 * 64 * 4);
    float* u1    = (float*)alloc((size_t)K1 * 64 * 4);

    float* xf  = arenaA;
    float* xp1 = arenaA;
    float* xp2 = arenaA;
    float* x3  = arenaA + (size_t)10485760 / 4;
    float* x4  = arenaA;
    float* x5  = arenaA;

    const int* src0 = ei;
    const int* dst0 = ei + E0;

    auto g = [](long long n, int b) -> unsigned { return (unsigned)((n + b - 1) / b); };

    // ---- dtype detect + conversions ----
    detect_dtype_kernel<<<1, 256, 0, stream>>>((const unsigned*)x_raw, 4096, flag);
    to_f32_kernel<<<g((long long)N0 * FEAT, 256), 256, 0, stream>>>(x_raw, xf, N0 * FEAT, flag);
    to_f32_t_kernel<<<g(HID * FEAT, 256), 256, 0, stream>>>(w1_rel,  w1rT, HID, FEAT, flag);
    to_f32_t_kernel<<<g(HID * FEAT, 256), 256, 0, stream>>>(w1_root, w1tT, HID, FEAT, flag);
    to_f32_t_kernel<<<g(EMB * HID, 256), 256, 0, stream>>>(w2_rel,  w2rT, EMB, HID, flag);
    to_f32_t_kernel<<<g(EMB * HID, 256), 256, 0, stream>>>(w2_root, w2tT, EMB, HID, flag);
    to_f32_t_kernel<<<g(EMB * EMB, 256), 256, 0, stream>>>(w3_rel,  w3rT, EMB, EMB, flag);
    to_f32_t_kernel<<<g(EMB * EMB, 256), 256, 0, stream>>>(w3_root, w3tT, EMB, EMB, flag);
    to_f32_t_kernel<<<g(HID * EMB, 256), 256, 0, stream>>>(w4_rel,  w4rT, HID, EMB, flag);
    to_f32_t_kernel<<<g(HID * EMB, 256), 256, 0, stream>>>(w4_root, w4tT, HID, EMB, flag);
    to_f32_t_kernel<<<g(FEAT * HID, 256), 256, 0, stream>>>(w5_rel,  w5rT, FEAT, HID, flag);
    to_f32_t_kernel<<<g(FEAT * HID, 256), 256, 0, stream>>>(w5_root, w5tT, FEAT, HID, flag);
    to_f32_kernel<<<1, 256, 0, stream>>>(b1, b1f, HID, flag);
    to_f32_kernel<<<1, 256, 0, stream>>>(b2, b2f, EMB, flag);
    to_f32_kernel<<<1, 256, 0, stream>>>(b3, b3f, EMB, flag);
    to_f32_kernel<<<1, 256, 0, stream>>>(b4, b4f, HID, flag);
    to_f32_kernel<<<1, 256, 0, stream>>>(b5, b5f, FEAT, flag);
    to_f32_kernel<<<1, 256, 0, stream>>>(p1w, p1f, HID, flag);
    to_f32_kernel<<<1, 256, 0, stream>>>(p2w, p2f, EMB, flag);
    to_f32_kernel<<<g(NCLS * FEAT, 256), 256, 0, stream>>>(lw, lwf, NCLS * FEAT, flag);
    to_f32_kernel<<<1, 256, 0, stream>>>(lb, lbf, NCLS, flag);

    // ---- CSR graph0 ----
    hipMemsetAsync(deg, 0, (size_t)N0 * 4, stream);
    deg_count_kernel<<<g(E0, 256), 256, 0, stream>>>(src0, dst0, E0, nullptr, nullptr, deg);
    exclusive_scan_kernel<<<1, 1024, 0, stream>>>(deg, rp0, N0);
    copy_int_kernel<<<g(N0, 256), 256, 0, stream>>>(rp0, cursor, N0);
    csr_fill_kernel<<<g(E0, 256), 256, 0, stream>>>(src0, dst0, E0, nullptr, nullptr, cursor, cols0);

    // ---- Layer 1 ----
    aggregate_kernel<128><<<g(N0, 8), 256, 0, stream>>>(rp0, cols0, xf, agg, N0);
    linear_relu_kernel<128, 128><<<g(N0, 8), 256, 0, stream>>>(N0, agg, w1rT, xf, w1tT, b1f, x1);

    // ---- Pool 1 ----
    score_kernel<128><<<g(N0, 4), 256, 0, stream>>>(x1, p1f, N0, score);
    build_keys_kernel<<<g(N0, 256), 256, 0, stream>>>(score, keys, N0);
    hipMemsetAsync(rank, 0, (size_t)N0 * 4, stream);
    {
        dim3 grid(g(N0, 256), g(N0, RT));
        rank_count_kernel<<<grid, 256, 0, stream>>>(keys, N0, rank);
    }
    finalize_perm_kernel<<<g(N0, 256), 256, 0, stream>>>(rank, N0, K1, perm1, map1);
    pool_apply_kernel<128><<<g((long long)K1 * 32, 256), 256, 0, stream>>>(x1, score, perm1, xp1, K1);

    // ---- CSR graph1 ----
    hipMemsetAsync(deg, 0, (size_t)K1 * 4, stream);
    deg_count_kernel<<<g(E0, 256), 256, 0, stream>>>(src0, dst0, E0, map1, nullptr, deg);
    exclusive_scan_kernel<<<1, 1024, 0, stream>>>(deg, rp1, K1);
    copy_int_kernel<<<g(K1, 256), 256, 0, stream>>>(rp1, cursor, K1);
    csr_fill_kernel<<<g(E0, 256), 256, 0, stream>>>(src0, dst0, E0, map1, nullptr, cursor, cols1);

    // ---- Layer 2 ----
    aggregate_kernel<128><<<g(K1, 8), 256, 0, stream>>>(rp1, cols1, xp1, agg, K1);
    linear_relu_kernel<128, 64><<<g(K1, 16), 256, 0, stream>>>(K1, agg, w2rT, xp1, w2tT, b2f, x2);

    // ---- Pool 2 ----
    score_kernel<64><<<g(K1, 4), 256, 0, stream>>>(x2, p2f, K1, score);
    build_keys_kernel<<<g(K1, 256), 256, 0, stream>>>(score, keys, K1);
    hipMemsetAsync(rank, 0, (size_t)K1 * 4, stream);
    {
        dim3 grid(g(K1, 256), g(K1, RT));
        rank_count_kernel<<<grid, 256, 0, stream>>>(keys, K1, rank);
    }
    finalize_perm_kernel<<<g(K1, 256), 256, 0, stream>>>(rank, K1, K2, perm2, map2);
    pool_apply_kernel<64><<<g((long long)K2 * 16, 256), 256, 0, stream>>>(x2, score, perm2, xp2, K2);

    // ---- CSR graph2 ----
    hipMemsetAsync(deg, 0, (size_t)K2 * 4, stream);
    deg_count_kernel<<<g(E0, 256), 256, 0, stream>>>(src0, dst0, E0, map1, map2, deg);
    exclusive_scan_kernel<<<1, 1024, 0, stream>>>(deg, rp2, K2);
    copy_int_kernel<<<g(K2, 256), 256, 0, stream>>>(rp2, cursor, K2);
    csr_fill_kernel<<<g(E0, 256), 256, 0, stream>>>(src0, dst0, E0, map1, map2, cursor, cols2);

    // ---- Layer 3 ----
    aggregate_kernel<64><<<g(K2, 16), 256, 0, stream>>>(rp2, cols2, xp2, agg, K2);
    linear_relu_kernel<64, 64><<<g(K2, 16), 256, 0, stream>>>(K2, agg, w3rT, xp2, w3tT, b3f, x3);

    // ---- Unpool 1 ----
    unpool_add_kernel<64><<<g((long long)K1 * 16, 256), 256, 0, stream>>>(x2, x3, map2, u1, K1);

    // ---- Layer 4 ----
    aggregate_kernel<64><<<g(K1, 16), 256, 0, stream>>>(rp1, cols1, u1, agg, K1);
    linear_relu_kernel<64, 128><<<g(K1, 8), 256, 0, stream>>>(K1, agg, w4rT, u1, w4tT, b4f, x4);

    // ---- Unpool 2 (in-place on x1) ----
    unpool_add_kernel<128><<<g((long long)N0 * 32, 256), 256, 0, stream>>>(x1, x4, map1, x1, N0);

    // ---- Layer 5 ----
    aggregate_kernel<128><<<g(N0, 8), 256, 0, stream>>>(rp0, cols0, x1, agg, N0);
    linear_relu_kernel<128, 128><<<g(N0, 8), 256, 0, stream>>>(N0, agg, w5rT, x1, w5tT, b5f, x5);

    // ---- Head ----
    head_kernel<<<g(N0, 4), 256, 0, stream>>>(x5, lwf, lbf, d_out, N0, flag);
}

// Round 6
// 1806.792 us; speedup vs baseline: 1.5885x; 1.2799x over previous
//
#include <hip/hip_runtime.h>
#include <hip/hip_bf16.h>
#include <math.h>

#define N0 50000
#define E0 1600000
#define K1 40000
#define K2 32000
#define FEAT 128
#define HID 128
#define EMB 64
#define NCLS 10

typedef __bf16 v8bf __attribute__((ext_vector_type(8)));
typedef __bf16 v4bf __attribute__((ext_vector_type(4)));
typedef float  v4f  __attribute__((ext_vector_type(4)));

static __device__ __forceinline__ unsigned f2key(float f) {
    unsigned u = __float_as_uint(f);
    return (u & 0x80000000u) ? ~u : (u | 0x80000000u);
}

// ---------- dtype detection ----------
__global__ void detect_dtype_kernel(const unsigned* __restrict__ w, int n, int* __restrict__ flag) {
    __shared__ int tot;
    if (threadIdx.x == 0) tot = 0;
    __syncthreads();
    int cnt = 0;
    for (int i = threadIdx.x; i < n; i += 256) {
        unsigned lo = w[i] & 0xFFFFu;
        unsigned e = (lo >> 7) & 0xFFu;
        cnt += (e >= 143);
    }
    atomicAdd(&tot, cnt);
    __syncthreads();
    if (threadIdx.x == 0) flag[0] = (tot > n / 8) ? 1 : 0;  // 1 = f32, 0 = bf16
}

static __device__ __forceinline__ float load_as_f32(const void* in, long long i, int isF32) {
    if (isF32) return ((const float*)in)[i];
    unsigned short h = ((const unsigned short*)in)[i];
    return __uint_as_float(((unsigned)h) << 16);
}

__global__ void to_f32_kernel(const void* __restrict__ in, float* __restrict__ out, int n,
                              const int* __restrict__ flag) {
    int i = blockIdx.x * 256 + threadIdx.x;
    if (i < n) out[i] = load_as_f32(in, i, *flag);
}

// f32 value -> (hi, lo) bf16 pair
__global__ void to_split_kernel(const void* __restrict__ in, __bf16* __restrict__ hi,
                                __bf16* __restrict__ lo, int n, const int* __restrict__ flag) {
    int i = blockIdx.x * 256 + threadIdx.x;
    if (i >= n) return;
    float v = load_as_f32(in, i, *flag);
    __bf16 h = (__bf16)v;
    hi[i] = h;
    lo[i] = (__bf16)(v - (float)h);
}

// ---------- CSR build ----------
__global__ void deg_count_kernel(const int* __restrict__ src, const int* __restrict__ dst, int E,
                                 const int* __restrict__ m1, const int* __restrict__ m2,
                                 int* __restrict__ deg) {
    int e = blockIdx.x * 256 + threadIdx.x;
    if (e >= E) return;
    int s = src[e], d = dst[e];
    if (m1) { s = m1[s]; d = m1[d]; if (s < 0 || d < 0) return; }
    if (m2) { s = m2[s]; d = m2[d]; if (s < 0 || d < 0) return; }
    atomicAdd(&deg[d], 1);
}

__global__ void csr_fill_kernel(const int* __restrict__ src, const int* __restrict__ dst, int E,
                                const int* __restrict__ m1, const int* __restrict__ m2,
                                int* __restrict__ cursor, int* __restrict__ cols) {
    int e = blockIdx.x * 256 + threadIdx.x;
    if (e >= E) return;
    int s = src[e], d = dst[e];
    if (m1) { s = m1[s]; d = m1[d]; if (s < 0 || d < 0) return; }
    if (m2) { s = m2[s]; d = m2[d]; if (s < 0 || d < 0) return; }
    int p = atomicAdd(&cursor[d], 1);
    cols[p] = s;
}

__global__ void exclusive_scan_kernel(const int* __restrict__ deg, int* __restrict__ rowptr, int M) {
    __shared__ int part[1024];
    int t = threadIdx.x;
    int per = (M + 1023) / 1024;
    int s = 0;
    for (int k = 0; k < per; ++k) { int idx = t * per + k; if (idx < M) s += deg[idx]; }
    part[t] = s;
    __syncthreads();
    for (int off = 1; off < 1024; off <<= 1) {
        int v = 0;
        if (t >= off) v = part[t - off];
        __syncthreads();
        if (t >= off) part[t] += v;
        __syncthreads();
    }
    int run = (t > 0) ? part[t - 1] : 0;
    for (int k = 0; k < per; ++k) {
        int idx = t * per + k;
        if (idx < M) { rowptr[idx] = run; run += deg[idx]; }
    }
    if (t == 1023) rowptr[M] = part[1023];
}

__global__ void copy_int_kernel(const int* __restrict__ in, int* __restrict__ out, int n) {
    int i = blockIdx.x * 256 + threadIdx.x;
    if (i < n) out[i] = in[i];
}

// ---------- gather aggregation: f32 gather/accumulate, hi/lo bf16 out ----------
template<int C>
__global__ void aggregate_kernel(const int* __restrict__ rowptr, const int* __restrict__ cols,
                                 const float* __restrict__ x, __bf16* __restrict__ aggHi,
                                 __bf16* __restrict__ aggLo, int M) {
    const int CH = C / 4;
    const int NPB = 256 / CH;
    int n = blockIdx.x * NPB + threadIdx.x / CH;
    int c4 = threadIdx.x % CH;
    if (n >= M) return;
    int b = rowptr[n], e = rowptr[n + 1];
    float4 s = {0.f, 0.f, 0.f, 0.f};
    for (int j = b; j < e; ++j) {
        int src = cols[j];
        float4 v = ((const float4*)(x + (size_t)src * C))[c4];
        s.x += v.x; s.y += v.y; s.z += v.z; s.w += v.w;
    }
    v4bf h, l;
    h[0] = (__bf16)s.x; l[0] = (__bf16)(s.x - (float)h[0]);
    h[1] = (__bf16)s.y; l[1] = (__bf16)(s.y - (float)h[1]);
    h[2] = (__bf16)s.z; l[2] = (__bf16)(s.z - (float)h[2]);
    h[3] = (__bf16)s.w; l[3] = (__bf16)(s.w - (float)h[3]);
    *(v4bf*)(aggHi + (size_t)n * C + c4 * 4) = h;
    *(v4bf*)(aggLo + (size_t)n * C + c4 * 4) = l;
}

// ---------- split-precision MFMA dual linear + bias + relu ----------
// product = ah*bh + ah*bl + al*bh (al*bl dropped, ~2^-18 rel)
template<int Cin, int Cout>
__global__ void linear_mfma_kernel(int M,
                                   const __bf16* __restrict__ Ahi, const __bf16* __restrict__ Alo,
                                   const __bf16* __restrict__ WaHi, const __bf16* __restrict__ WaLo,
                                   const __bf16* __restrict__ Bhi, const __bf16* __restrict__ Blo,
                                   const __bf16* __restrict__ WbHi, const __bf16* __restrict__ WbLo,
                                   const float* __restrict__ bias, float* __restrict__ outF) {
    constexpr int NG = Cout / 16;
    int wave = threadIdx.x >> 6;
    int lane = threadIdx.x & 63;
    int m = lane & 15, quad = lane >> 4;
    int row0 = blockIdx.x * 64 + wave * 16;
    int ra = row0 + m; if (ra > M - 1) ra = M - 1;

    v4f acc[NG];
#pragma unroll
    for (int g = 0; g < NG; ++g) acc[g] = (v4f){0.f, 0.f, 0.f, 0.f};

#pragma unroll
    for (int ks = 0; ks < Cin / 32; ++ks) {
        size_t aoff = (size_t)ra * Cin + ks * 32 + quad * 8;
        v8bf ah = *(const v8bf*)(Ahi + aoff);
        v8bf al = *(const v8bf*)(Alo + aoff);
#pragma unroll
        for (int g = 0; g < NG; ++g) {
            size_t woff = (size_t)(g * 16 + m) * Cin + ks * 32 + quad * 8;
            v8bf bh = *(const v8bf*)(WaHi + woff);
            v8bf bl = *(const v8bf*)(WaLo + woff);
            acc[g] = __builtin_amdgcn_mfma_f32_16x16x32_bf16(ah, bh, acc[g], 0, 0, 0);
            acc[g] = __builtin_amdgcn_mfma_f32_16x16x32_bf16(ah, bl, acc[g], 0, 0, 0);
            acc[g] = __builtin_amdgcn_mfma_f32_16x16x32_bf16(al, bh, acc[g], 0, 0, 0);
        }
    }
#pragma unroll
    for (int ks = 0; ks < Cin / 32; ++ks) {
        size_t aoff = (size_t)ra * Cin + ks * 32 + quad * 8;
        v8bf ah = *(const v8bf*)(Bhi + aoff);
        v8bf al = *(const v8bf*)(Blo + aoff);
#pragma unroll
        for (int g = 0; g < NG; ++g) {
            size_t woff = (size_t)(g * 16 + m) * Cin + ks * 32 + quad * 8;
            v8bf bh = *(const v8bf*)(WbHi + woff);
            v8bf bl = *(const v8bf*)(WbLo + woff);
            acc[g] = __builtin_amdgcn_mfma_f32_16x16x32_bf16(ah, bh, acc[g], 0, 0, 0);
            acc[g] = __builtin_amdgcn_mfma_f32_16x16x32_bf16(ah, bl, acc[g], 0, 0, 0);
            acc[g] = __builtin_amdgcn_mfma_f32_16x16x32_bf16(al, bh, acc[g], 0, 0, 0);
        }
    }

    // C/D layout: col = lane&15, row = quad*4 + reg
#pragma unroll
    for (int g = 0; g < NG; ++g) {
        int col = g * 16 + m;
        float bv = bias[col];
#pragma unroll
        for (int r = 0; r < 4; ++r) {
            int row = row0 + quad * 4 + r;
            if (row < M) outF[(size_t)row * Cout + col] = fmaxf(acc[g][r] + bv, 0.f);
        }
    }
}

// ---------- pooling score ----------
template<int C>
__global__ void score_kernel(const float* __restrict__ xin, const float* __restrict__ w,
                             int M, float* __restrict__ score) {
    int row = blockIdx.x * 4 + (threadIdx.x >> 6);
    int lane = threadIdx.x & 63;
    if (row >= M) return;
    float p = 0.f, q = 0.f;
#pragma unroll
    for (int c = lane; c < C; c += 64) {
        float wc = w[c];
        float xc = xin[(size_t)row * C + c];
        p += xc * wc; q += wc * wc;
    }
#pragma unroll
    for (int off = 32; off >= 1; off >>= 1) {
        p += __shfl_xor(p, off, 64);
        q += __shfl_xor(q, off, 64);
    }
    if (lane == 0) {
        float arg = p / sqrtf(q);
        score[row] = (float)tanh((double)arg);
    }
}

__global__ void build_keys_kernel(const float* __restrict__ score, unsigned long long* __restrict__ keys, int N) {
    int i = blockIdx.x * 256 + threadIdx.x;
    if (i < N) keys[i] = ((unsigned long long)f2key(score[i]) << 32) | (unsigned)(~i);
}

#define RT 4096
__global__ void rank_count_kernel(const unsigned long long* __restrict__ keys, int N, int* __restrict__ rank) {
    __shared__ unsigned long long sk[RT];
    int i = blockIdx.x * 256 + threadIdx.x;
    int j0 = blockIdx.y * RT;
    int tile = N - j0; if (tile > RT) tile = RT;
    for (int t = threadIdx.x; t < tile; t += 256) sk[t] = keys[j0 + t];
    __syncthreads();
    unsigned long long ci = (i < N) ? keys[i] : ~0ull;
    int cnt = 0;
    int t = 0;
    for (; t + 8 <= tile; t += 8) {
        cnt += (sk[t+0] > ci); cnt += (sk[t+1] > ci);
        cnt += (sk[t+2] > ci); cnt += (sk[t+3] > ci);
        cnt += (sk[t+4] > ci); cnt += (sk[t+5] > ci);
        cnt += (sk[t+6] > ci); cnt += (sk[t+7] > ci);
    }
    for (; t < tile; ++t) cnt += (sk[t] > ci);
    if (i < N && cnt) atomicAdd(&rank[i], cnt);
}

__global__ void finalize_perm_kernel(const int* __restrict__ rank, int N, int K,
                                     int* __restrict__ perm, int* __restrict__ mapping) {
    int i = blockIdx.x * 256 + threadIdx.x;
    if (i >= N) return;
    int r = rank[i];
    if (r < K) { perm[r] = i; mapping[i] = r; }
    else mapping[i] = -1;
}

// xp[j] = x[perm[j]] * score[perm[j]]  -> f32 + (hi,lo)
template<int C>
__global__ void pool_apply_kernel(const float* __restrict__ xin, const float* __restrict__ score,
                                  const int* __restrict__ perm, float* __restrict__ xpF,
                                  __bf16* __restrict__ xpHi, __bf16* __restrict__ xpLo, int K) {
    const int CH = C / 4;
    int tid = blockIdx.x * 256 + threadIdx.x;
    int j = tid / CH, c4 = tid % CH;
    if (j >= K) return;
    int src = perm[j];
    float s = score[src];
    float4 v = ((const float4*)(xin + (size_t)src * C))[c4];
    v.x *= s; v.y *= s; v.z *= s; v.w *= s;
    ((float4*)(xpF + (size_t)j * C))[c4] = v;
    v4bf h, l;
    h[0] = (__bf16)v.x; l[0] = (__bf16)(v.x - (float)h[0]);
    h[1] = (__bf16)v.y; l[1] = (__bf16)(v.y - (float)h[1]);
    h[2] = (__bf16)v.z; l[2] = (__bf16)(v.z - (float)h[2]);
    h[3] = (__bf16)v.w; l[3] = (__bf16)(v.w - (float)h[3]);
    *(v4bf*)(xpHi + (size_t)j * C + c4 * 4) = h;
    *(v4bf*)(xpLo + (size_t)j * C + c4 * 4) = l;
}

// u[j] = base[j] + (mapping[j]>=0 ? deep[mapping[j]] : 0)  -> f32 + (hi,lo); uF may alias base
template<int C>
__global__ void unpool_add_kernel(const float* __restrict__ base, const float* __restrict__ deep,
                                  const int* __restrict__ mapping, float* __restrict__ uF,
                                  __bf16* __restrict__ uHi, __bf16* __restrict__ uLo, int M) {
    const int CH = C / 4;
    int tid = blockIdx.x * 256 + threadIdx.x;
    int j = tid / CH, c4 = tid % CH;
    if (j >= M) return;
    float4 v = ((const float4*)(base + (size_t)j * C))[c4];
    int m = mapping[j];
    if (m >= 0) {
        float4 d = ((const float4*)(deep + (size_t)m * C))[c4];
        v.x += d.x; v.y += d.y; v.z += d.z; v.w += d.w;
    }
    ((float4*)(uF + (size_t)j * C))[c4] = v;
    v4bf h, l;
    h[0] = (__bf16)v.x; l[0] = (__bf16)(v.x - (float)h[0]);
    h[1] = (__bf16)v.y; l[1] = (__bf16)(v.y - (float)h[1]);
    h[2] = (__bf16)v.z; l[2] = (__bf16)(v.z - (float)h[2]);
    h[3] = (__bf16)v.w; l[3] = (__bf16)(v.w - (float)h[3]);
    *(v4bf*)(uHi + (size_t)j * C + c4 * 4) = h;
    *(v4bf*)(uLo + (size_t)j * C + c4 * 4) = l;
}

__global__ void head_kernel(const float* __restrict__ x5, const float* __restrict__ lw,
                            const float* __restrict__ lb, void* __restrict__ out, int M,
                            const int* __restrict__ flag) {
    int row = blockIdx.x * 4 + (threadIdx.x >> 6);
    int lane = threadIdx.x & 63;
    if (row >= M) return;
    float a0 = x5[(size_t)row * 128 + lane];
    float a1 = x5[(size_t)row * 128 + 64 + lane];
    float d[NCLS];
#pragma unroll
    for (int o = 0; o < NCLS; ++o) {
        float p = a0 * lw[o * 128 + lane] + a1 * lw[o * 128 + 64 + lane];
#pragma unroll
        for (int off = 32; off >= 1; off >>= 1) p += __shfl_xor(p, off, 64);
        d[o] = p + lb[o];
    }
    float mx = d[0];
#pragma unroll
    for (int o = 1; o < NCLS; ++o) mx = fmaxf(mx, d[o]);
    float s = 0.f;
#pragma unroll
    for (int o = 0; o < NCLS; ++o) s += expf(d[o] - mx);
    float lse = mx + logf(s);
    if (lane < NCLS) {
        float v = d[0];
#pragma unroll
        for (int o = 1; o < NCLS; ++o) if (lane == o) v = d[o];
        float r = v - lse;
        if (*flag) ((float*)out)[(size_t)row * NCLS + lane] = r;
        else ((__hip_bfloat16*)out)[(size_t)row * NCLS + lane] = __float2bfloat16(r);
    }
}

extern "C" void kernel_launch(void* const* d_in, const int* in_sizes, int n_in,
                              void* d_out, int out_size, void* d_ws, size_t ws_size,
                              hipStream_t stream) {
    const void* x_raw   = d_in[0];
    const int*  ei      = (const int*)d_in[1];
    const void* w1_rel  = d_in[2];
    const void* w1_root = d_in[3];
    const void* b1      = d_in[4];
    const void* p1w     = d_in[5];
    const void* w2_rel  = d_in[6];
    const void* w2_root = d_in[7];
    const void* b2      = d_in[8];
    const void* p2w     = d_in[9];
    const void* w3_rel  = d_in[10];
    const void* w3_root = d_in[11];
    const void* b3      = d_in[12];
    const void* w4_rel  = d_in[13];
    const void* w4_root = d_in[14];
    const void* b4      = d_in[15];
    const void* w5_rel  = d_in[16];
    const void* w5_root = d_in[17];
    const void* b5      = d_in[18];
    const void* lw      = d_in[19];
    const void* lb      = d_in[20];

    char* base = (char*)d_ws;
    size_t off = 0;
    auto alloc = [&](size_t bytes) -> void* {
        void* p = base + off;
        off = (off + bytes + 255) & ~(size_t)255;
        return p;
    };
    int* flag = (int*)alloc(256);
    // weight splits (~0.5 MB total)
    __bf16* w1rHi = (__bf16*)alloc(HID * FEAT * 2); __bf16* w1rLo = (__bf16*)alloc(HID * FEAT * 2);
    __bf16* w1tHi = (__bf16*)alloc(HID * FEAT * 2); __bf16* w1tLo = (__bf16*)alloc(HID * FEAT * 2);
    __bf16* w2rHi = (__bf16*)alloc(EMB * HID * 2);  __bf16* w2rLo = (__bf16*)alloc(EMB * HID * 2);
    __bf16* w2tHi = (__bf16*)alloc(EMB * HID * 2);  __bf16* w2tLo = (__bf16*)alloc(EMB * HID * 2);
    __bf16* w3rHi = (__bf16*)alloc(EMB * EMB * 2);  __bf16* w3rLo = (__bf16*)alloc(EMB * EMB * 2);
    __bf16* w3tHi = (__bf16*)alloc(EMB * EMB * 2);  __bf16* w3tLo = (__bf16*)alloc(EMB * EMB * 2);
    __bf16* w4rHi = (__bf16*)alloc(HID * EMB * 2);  __bf16* w4rLo = (__bf16*)alloc(HID * EMB * 2);
    __bf16* w4tHi = (__bf16*)alloc(HID * EMB * 2);  __bf16* w4tLo = (__bf16*)alloc(HID * EMB * 2);
    __bf16* w5rHi = (__bf16*)alloc(FEAT * HID * 2); __bf16* w5rLo = (__bf16*)alloc(FEAT * HID * 2);
    __bf16* w5tHi = (__bf16*)alloc(FEAT * HID * 2); __bf16* w5tLo = (__bf16*)alloc(FEAT * HID * 2);
    float* b1f = (float*)alloc(HID * 4);
    float* b2f = (float*)alloc(EMB * 4);
    float* b3f = (float*)alloc(EMB * 4);
    float* b4f = (float*)alloc(HID * 4);
    float* b5f = (float*)alloc(FEAT * 4);
    float* p1f = (float*)alloc(HID * 4);
    float* p2f = (float*)alloc(EMB * 4);
    float* lwf = (float*)alloc(NCLS * FEAT * 4);
    float* lbf = (float*)alloc(NCLS * 4);
    float* score = (float*)alloc((size_t)N0 * 4);
    unsigned long long* keys = (unsigned long long*)alloc((size_t)N0 * 8);
    int* rank  = (int*)alloc((size_t)N0 * 4);
    int* perm1 = (int*)alloc((size_t)K1 * 4);
    int* map1  = (int*)alloc((size_t)N0 * 4);
    int* perm2 = (int*)alloc((size_t)K2 * 4);
    int* map2  = (int*)alloc((size_t)K1 * 4);
    int* deg   = (int*)alloc((size_t)(N0 + 1) * 4);
    int* cursor= (int*)alloc((size_t)(N0 + 1) * 4);
    int* rp0   = (int*)alloc((size_t)(N0 + 1) * 4);
    int* rp1   = (int*)alloc((size_t)(K1 + 1) * 4);
    int* rp2   = (int*)alloc((size_t)(K2 + 1) * 4);
    int* cols0 = (int*)alloc((size_t)E0 * 4);
    int* cols1 = (int*)alloc((size_t)E0 * 4);
    int* cols2 = (int*)alloc((size_t)E0 * 4);
    // ---- aliased activation arenas (lifetimes disjoint within each arena) ----
    char*   arenaX  = (char*)alloc((size_t)N0 * 128 * 4);   // 25.6 MB: xf -> xp1f -> {xp2f, x3f} -> x4f -> x5f
    __bf16* arenaHi = (__bf16*)alloc((size_t)N0 * 128 * 2); // 12.8 MB: xHi -> xp1Hi -> xp2Hi -> u1Hi -> u2Hi
    __bf16* arenaLo = (__bf16*)alloc((size_t)N0 * 128 * 2); // 12.8 MB: xLo -> xp1Lo -> xp2Lo -> u1Lo -> u2Lo
    __bf16* aggHi   = (__bf16*)alloc((size_t)N0 * 128 * 2);
    __bf16* aggLo   = (__bf16*)alloc((size_t)N0 * 128 * 2);
    float*  x1f     = (float*)alloc((size_t)N0 * 128 * 4);  // persists; becomes u2 f32 in-place
    float*  x2f     = (float*)alloc((size_t)K1 * 64 * 4);   // persists; becomes u1 f32 in-place

    float* xf   = (float*)arenaX;
    float* xp1f = (float*)arenaX;
    float* xp2f = (float*)arenaX;                       // 8.192 MB
    float* x3f  = (float*)(arenaX + 8388608);           // 8 MiB offset, past xp2f
    float* x4f  = (float*)arenaX;
    float* x5f  = (float*)arenaX;
    __bf16 *xHi = arenaHi,  *xLo = arenaLo;
    __bf16 *xp1Hi = arenaHi, *xp1Lo = arenaLo;
    __bf16 *xp2Hi = arenaHi, *xp2Lo = arenaLo;
    __bf16 *u1Hi = arenaHi,  *u1Lo = arenaLo;
    __bf16 *u2Hi = arenaHi,  *u2Lo = arenaLo;
    float* u1f = x2f;   // unpool1 in-place

    const int* src0 = ei;
    const int* dst0 = ei + E0;

    auto g = [](long long n, int b) -> unsigned { return (unsigned)((n + b - 1) / b); };

    // ---- dtype detect + conversions ----
    detect_dtype_kernel<<<1, 256, 0, stream>>>((const unsigned*)x_raw, 4096, flag);
    to_f32_kernel<<<g((long long)N0 * FEAT, 256), 256, 0, stream>>>(x_raw, xf, N0 * FEAT, flag);
    to_split_kernel<<<g((long long)N0 * FEAT, 256), 256, 0, stream>>>(x_raw, xHi, xLo, N0 * FEAT, flag);
    to_split_kernel<<<g(HID * FEAT, 256), 256, 0, stream>>>(w1_rel,  w1rHi, w1rLo, HID * FEAT, flag);
    to_split_kernel<<<g(HID * FEAT, 256), 256, 0, stream>>>(w1_root, w1tHi, w1tLo, HID * FEAT, flag);
    to_split_kernel<<<g(EMB * HID, 256), 256, 0, stream>>>(w2_rel,  w2rHi, w2rLo, EMB * HID, flag);
    to_split_kernel<<<g(EMB * HID, 256), 256, 0, stream>>>(w2_root, w2tHi, w2tLo, EMB * HID, flag);
    to_split_kernel<<<g(EMB * EMB, 256), 256, 0, stream>>>(w3_rel,  w3rHi, w3rLo, EMB * EMB, flag);
    to_split_kernel<<<g(EMB * EMB, 256), 256, 0, stream>>>(w3_root, w3tHi, w3tLo, EMB * EMB, flag);
    to_split_kernel<<<g(HID * EMB, 256), 256, 0, stream>>>(w4_rel,  w4rHi, w4rLo, HID * EMB, flag);
    to_split_kernel<<<g(HID * EMB, 256), 256, 0, stream>>>(w4_root, w4tHi, w4tLo, HID * EMB, flag);
    to_split_kernel<<<g(FEAT * HID, 256), 256, 0, stream>>>(w5_rel,  w5rHi, w5rLo, FEAT * HID, flag);
    to_split_kernel<<<g(FEAT * HID, 256), 256, 0, stream>>>(w5_root, w5tHi, w5tLo, FEAT * HID, flag);
    to_f32_kernel<<<1, 256, 0, stream>>>(b1, b1f, HID, flag);
    to_f32_kernel<<<1, 256, 0, stream>>>(b2, b2f, EMB, flag);
    to_f32_kernel<<<1, 256, 0, stream>>>(b3, b3f, EMB, flag);
    to_f32_kernel<<<1, 256, 0, stream>>>(b4, b4f, HID, flag);
    to_f32_kernel<<<1, 256, 0, stream>>>(b5, b5f, FEAT, flag);
    to_f32_kernel<<<1, 256, 0, stream>>>(p1w, p1f, HID, flag);
    to_f32_kernel<<<1, 256, 0, stream>>>(p2w, p2f, EMB, flag);
    to_f32_kernel<<<g(NCLS * FEAT, 256), 256, 0, stream>>>(lw, lwf, NCLS * FEAT, flag);
    to_f32_kernel<<<1, 256, 0, stream>>>(lb, lbf, NCLS, flag);

    // ---- CSR graph0 ----
    hipMemsetAsync(deg, 0, (size_t)N0 * 4, stream);
    deg_count_kernel<<<g(E0, 256), 256, 0, stream>>>(src0, dst0, E0, nullptr, nullptr, deg);
    exclusive_scan_kernel<<<1, 1024, 0, stream>>>(deg, rp0, N0);
    copy_int_kernel<<<g(N0, 256), 256, 0, stream>>>(rp0, cursor, N0);
    csr_fill_kernel<<<g(E0, 256), 256, 0, stream>>>(src0, dst0, E0, nullptr, nullptr, cursor, cols0);

    // ---- Layer 1 ----
    aggregate_kernel<128><<<g(N0, 8), 256, 0, stream>>>(rp0, cols0, xf, aggHi, aggLo, N0);
    linear_mfma_kernel<128, 128><<<g(N0, 64), 256, 0, stream>>>(N0, aggHi, aggLo, w1rHi, w1rLo,
                                                                xHi, xLo, w1tHi, w1tLo, b1f, x1f);

    // ---- Pool 1 ----
    score_kernel<128><<<g(N0, 4), 256, 0, stream>>>(x1f, p1f, N0, score);
    build_keys_kernel<<<g(N0, 256), 256, 0, stream>>>(score, keys, N0);
    hipMemsetAsync(rank, 0, (size_t)N0 * 4, stream);
    {
        dim3 grid(g(N0, 256), g(N0, RT));
        rank_count_kernel<<<grid, 256, 0, stream>>>(keys, N0, rank);
    }
    finalize_perm_kernel<<<g(N0, 256), 256, 0, stream>>>(rank, N0, K1, perm1, map1);
    pool_apply_kernel<128><<<g((long long)K1 * 32, 256), 256, 0, stream>>>(x1f, score, perm1, xp1f, xp1Hi, xp1Lo, K1);

    // ---- CSR graph1 ----
    hipMemsetAsync(deg, 0, (size_t)K1 * 4, stream);
    deg_count_kernel<<<g(E0, 256), 256, 0, stream>>>(src0, dst0, E0, map1, nullptr, deg);
    exclusive_scan_kernel<<<1, 1024, 0, stream>>>(deg, rp1, K1);
    copy_int_kernel<<<g(K1, 256), 256, 0, stream>>>(rp1, cursor, K1);
    csr_fill_kernel<<<g(E0, 256), 256, 0, stream>>>(src0, dst0, E0, map1, nullptr, cursor, cols1);

    // ---- Layer 2 ----
    aggregate_kernel<128><<<g(K1, 8), 256, 0, stream>>>(rp1, cols1, xp1f, aggHi, aggLo, K1);
    linear_mfma_kernel<128, 64><<<g(K1, 64), 256, 0, stream>>>(K1, aggHi, aggLo, w2rHi, w2rLo,
                                                               xp1Hi, xp1Lo, w2tHi, w2tLo, b2f, x2f);

    // ---- Pool 2 ----
    score_kernel<64><<<g(K1, 4), 256, 0, stream>>>(x2f, p2f, K1, score);
    build_keys_kernel<<<g(K1, 256), 256, 0, stream>>>(score, keys, K1);
    hipMemsetAsync(rank, 0, (size_t)K1 * 4, stream);
    {
        dim3 grid(g(K1, 256), g(K1, RT));
        rank_count_kernel<<<grid, 256, 0, stream>>>(keys, K1, rank);
    }
    finalize_perm_kernel<<<g(K1, 256), 256, 0, stream>>>(rank, K1, K2, perm2, map2);
    pool_apply_kernel<64><<<g((long long)K2 * 16, 256), 256, 0, stream>>>(x2f, score, perm2, xp2f, xp2Hi, xp2Lo, K2);

    // ---- CSR graph2 ----
    hipMemsetAsync(deg, 0, (size_t)K2 * 4, stream);
    deg_count_kernel<<<g(E0, 256), 256, 0, stream>>>(src0, dst0, E0, map1, map2, deg);
    exclusive_scan_kernel<<<1, 1024, 0, stream>>>(deg, rp2, K2);
    copy_int_kernel<<<g(K2, 256), 256, 0, stream>>>(rp2, cursor, K2);
    csr_fill_kernel<<<g(E0, 256), 256, 0, stream>>>(src0, dst0, E0, map1, map2, cursor, cols2);

    // ---- Layer 3 ----
    aggregate_kernel<64><<<g(K2, 16), 256, 0, stream>>>(rp2, cols2, xp2f, aggHi, aggLo, K2);
    linear_mfma_kernel<64, 64><<<g(K2, 64), 256, 0, stream>>>(K2, aggHi, aggLo, w3rHi, w3rLo,
                                                              xp2Hi, xp2Lo, w3tHi, w3tLo, b3f, x3f);

    // ---- Unpool 1 (in-place on x2f; writes u1 hi/lo into arenaHi/Lo) ----
    unpool_add_kernel<64><<<g((long long)K1 * 16, 256), 256, 0, stream>>>(x2f, x3f, map2, u1f, u1Hi, u1Lo, K1);

    // ---- Layer 4 ----
    aggregate_kernel<64><<<g(K1, 16), 256, 0, stream>>>(rp1, cols1, u1f, aggHi, aggLo, K1);
    linear_mfma_kernel<64, 128><<<g(K1, 64), 256, 0, stream>>>(K1, aggHi, aggLo, w4rHi, w4rLo,
                                                               u1Hi, u1Lo, w4tHi, w4tLo, b4f, x4f);

    // ---- Unpool 2 (f32 in-place on x1f) ----
    unpool_add_kernel<128><<<g((long long)N0 * 32, 256), 256, 0, stream>>>(x1f, x4f, map1, x1f, u2Hi, u2Lo, N0);

    // ---- Layer 5 ----
    aggregate_kernel<128><<<g(N0, 8), 256, 0, stream>>>(rp0, cols0, x1f, aggHi, aggLo, N0);
    linear_mfma_kernel<128, 128><<<g(N0, 64), 256, 0, stream>>>(N0, aggHi, aggLo, w5rHi, w5rLo,
                                                                u2Hi, u2Lo, w5tHi, w5tLo, b5f, x5f);

    // ---- Head ----
    head_kernel<<<g(N0, 4), 256, 0, stream>>>(x5f, lwf, lbf, d_out, N0, flag);
}